// Round 29
// baseline (301.845 us; speedup 1.0000x reference)
//
#include <hip/hip_runtime.h>
#include <hip/hip_bf16.h>
#include <cstddef>

#define BB      32
#define TT_ALL  2048
#define EPROJS  1024
#define DUNITS  1024
#define ATT     512
#define CH      10
#define KS      201
#define FILT    100

// Output chunks (FP32): c | w | h_new | c_new
#define OFF_C   0
#define OFF_W   (BB*EPROJS)
#define OFF_H   (OFF_W + BB*TT_ALL)
#define OFF_CN  (OFF_H + BB*ATT)

// ws layout (float offsets)
#define WS_CF    0
#define WS_V     512
#define WS_EP    16896                 // e partials: 2 x 65536
#define WS_WF    147968                // w fp32: 65536
#define WS_WT    213504                // WTF bf16 (512x1024) = 262144 f32 slots
#define WS_PART  475648                // ctx partials: 262144
#define WS_GP    737792                // gates partials: 131072
#define WS_DP    868864                // dec partials: 32768

typedef __attribute__((ext_vector_type(8))) short short8;
typedef __attribute__((ext_vector_type(4))) float f32x4;

__device__ __forceinline__ float sigm(float x) { return 1.f / (1.f + expf(-x)); }
__device__ __forceinline__ unsigned short f2bf(float f) {
  unsigned u = __float_as_uint(f);
  return (unsigned short)((u + 0x7FFFu + ((u >> 16) & 1u)) >> 16);  // RNE
}
__device__ __forceinline__ ushort2 f2bf2(float a, float b) {
  __hip_bfloat162 h = __float22bfloat162_rn(float2{a, b});
  return *reinterpret_cast<ushort2*>(&h);
}
__device__ __forceinline__ short8 pack_bf16x8(const float4 a, const float4 b) {
  union { short8 s; ushort2 u[4]; } r;
  r.u[0] = f2bf2(a.x, a.y); r.u[1] = f2bf2(a.z, a.w);
  r.u[2] = f2bf2(b.x, b.y); r.u[3] = f2bf2(b.z, b.w);
  return r.s;
}

// ---------------------------------------------------------------------------
// K0: W_enc (E,A) fp32 -> WTF fragment-major bf16 (B-operand).
__global__ __launch_bounds__(64) void k_wprepF(const float* __restrict__ W,
                                               unsigned short* __restrict__ WTF) {
  const int r16 = blockIdx.x >> 5, ks = blockIdx.x & 31;
  const int l = threadIdx.x;
  const int a = r16 * 16 + (l & 15);
  const int e0 = ks * 32 + (l >> 4) * 8;
  union { short8 s; unsigned short h[8]; } r;
#pragma unroll
  for (int j = 0; j < 8; ++j) r.h[j] = f2bf(W[(size_t)(e0 + j) * ATT + a]);
  *reinterpret_cast<short8*>(&WTF[((size_t)(r16 * 32 + ks) * 64 + l) * 8]) = r.s;
}

// ---------------------------------------------------------------------------
// K1: location conv -> relu -> max over T
__global__ __launch_bounds__(256) void k_conv(const float* __restrict__ att_prev,
                                              const float* __restrict__ W_conv,
                                              float* __restrict__ conv_feat) {
  const int b  = blockIdx.x / CH;
  const int ch = blockIdx.x % CH;
  __shared__ float sprev[TT_ALL + 2 * FILT];
  __shared__ float sw[KS];
  __shared__ float red[4];
  const int tid = threadIdx.x;
  for (int i = tid; i < TT_ALL + 2 * FILT; i += 256) {
    int t = i - FILT;
    sprev[i] = (t >= 0 && t < TT_ALL) ? att_prev[b * TT_ALL + t] : 0.f;
  }
  for (int i = tid; i < KS; i += 256) sw[i] = W_conv[ch * KS + i];
  __syncthreads();
  float m = 0.f;
  for (int t = tid; t < TT_ALL; t += 256) {
    float s = 0.f;
    for (int k = 0; k < KS; ++k) s = fmaf(sprev[t + k], sw[k], s);
    m = fmaxf(m, s);
  }
  for (int off = 32; off; off >>= 1) m = fmaxf(m, __shfl_xor(m, off, 64));
  if ((tid & 63) == 0) red[tid >> 6] = m;
  __syncthreads();
  if (tid == 0)
    conv_feat[b * CH + ch] = fmaxf(fmaxf(red[0], red[1]), fmaxf(red[2], red[3]));
}

// ---------------------------------------------------------------------------
// K2a: gates partial
__global__ __launch_bounds__(256) void k_gates(const float* __restrict__ att_h,
                                               const float* __restrict__ W_hh,
                                               float* __restrict__ gp) {
  const int jt = blockIdx.x >> 1;
  const int sp = blockIdx.x & 1;
  const int j0 = jt * 64;
  const int k0 = sp * 256;
  const int tid = threadIdx.x;
  const int al = tid & 63, bg = tid >> 6;
  __shared__ float sW[64][65];
  __shared__ float sH[32][64];
  float acc[8];
#pragma unroll
  for (int i = 0; i < 8; ++i) acc[i] = 0.f;
  for (int kc = 0; kc < 256; kc += 64) {
    __syncthreads();
#pragma unroll
    for (int i = 0; i < 4; ++i) {
      const int f = tid + i * 256;
      const int r = f >> 4, q = f & 15;
      const float4 w4 = *reinterpret_cast<const float4*>(
          &W_hh[(size_t)(j0 + r) * ATT + k0 + kc + q * 4]);
      sW[r][q * 4 + 0] = w4.x; sW[r][q * 4 + 1] = w4.y;
      sW[r][q * 4 + 2] = w4.z; sW[r][q * 4 + 3] = w4.w;
    }
#pragma unroll
    for (int i = 0; i < 2; ++i) {
      const int g = tid + i * 256;
      const int r = g >> 4, q = g & 15;
      *reinterpret_cast<float4*>(&sH[r][q * 4]) = *reinterpret_cast<const float4*>(
          &att_h[(size_t)r * ATT + k0 + kc + q * 4]);
    }
    __syncthreads();
#pragma unroll 16
    for (int k = 0; k < 64; ++k) {
      const float w = sW[al][k];
#pragma unroll
      for (int bb = 0; bb < 8; ++bb)
        acc[bb] = fmaf(w, sH[bg * 8 + bb][k], acc[bb]);
    }
  }
#pragma unroll
  for (int bb = 0; bb < 8; ++bb)
    gp[((size_t)(sp * 32 + bg * 8 + bb)) * (4 * ATT) + j0 + al] = acc[bb];
}

// ---------------------------------------------------------------------------
// K2b: dec partial
__global__ __launch_bounds__(256) void k_dec(const float* __restrict__ dec_z,
                                             const float* __restrict__ W_dec,
                                             float* __restrict__ dp) {
  const int at = blockIdx.x >> 1;
  const int sp = blockIdx.x & 1;
  const int a0 = at * 64;
  const int d0 = sp * 512;
  const int tid = threadIdx.x;
  const int al = tid & 63, bg = tid >> 6;
  __shared__ float sW[64][64];
  __shared__ float sZ[32][64];
  float acc[8];
#pragma unroll
  for (int i = 0; i < 8; ++i) acc[i] = 0.f;
  for (int dc = 0; dc < 512; dc += 64) {
    __syncthreads();
#pragma unroll
    for (int i = 0; i < 4; ++i) {
      const int f = tid + i * 256;
      const int r = f >> 4, q = f & 15;
      *reinterpret_cast<float4*>(&sW[r][q * 4]) = *reinterpret_cast<const float4*>(
          &W_dec[(size_t)(d0 + dc + r) * ATT + a0 + q * 4]);
    }
#pragma unroll
    for (int i = 0; i < 2; ++i) {
      const int g = tid + i * 256;
      const int r = g >> 4, q = g & 15;
      *reinterpret_cast<float4*>(&sZ[r][q * 4]) = *reinterpret_cast<const float4*>(
          &dec_z[(size_t)r * DUNITS + d0 + dc + q * 4]);
    }
    __syncthreads();
#pragma unroll 16
    for (int d = 0; d < 64; ++d) {
      const float w = sW[d][al];
#pragma unroll
      for (int bb = 0; bb < 8; ++bb)
        acc[bb] = fmaf(sZ[bg * 8 + bb][d], w, acc[bb]);
    }
  }
#pragma unroll
  for (int bb = 0; bb < 8; ++bb)
    dp[((size_t)(sp * 32 + bg * 8 + bb)) * ATT + a0 + al] = acc[bb];
}

// ---------------------------------------------------------------------------
// K2c: combine + LSTM + v
__global__ __launch_bounds__(256) void k_lstm_v(const float* __restrict__ gp,
                                                const float* __restrict__ dp,
                                                const float* __restrict__ conv_feat,
                                                const float* __restrict__ W_ih,
                                                const float* __restrict__ att_c,
                                                float* __restrict__ v,
                                                float* __restrict__ out) {
  const int b = blockIdx.x, tid = threadIdx.x;
  __shared__ float scf[CH];
  if (tid < CH) scf[tid] = conv_feat[b * CH + tid];
  __syncthreads();
  for (int a = tid; a < ATT; a += 256) {
    float g4[4];
#pragma unroll
    for (int q = 0; q < 4; ++q) {
      const int j = q * ATT + a;
      float g = gp[(size_t)b * (4 * ATT) + j] + gp[(size_t)(32 + b) * (4 * ATT) + j];
#pragma unroll
      for (int c = 0; c < CH; ++c) g = fmaf(scf[c], W_ih[(size_t)j * CH + c], g);
      g4[q] = g;
    }
    const float ig = sigm(g4[0]);
    const float fg = sigm(g4[1]);
    const float gg = tanhf(g4[2]);
    const float og = sigm(g4[3]);
    const float cN = fg * att_c[b * ATT + a] + ig * gg;
    const float hN = og * tanhf(cN);
    out[OFF_H + b * ATT + a]  = hN;
    out[OFF_CN + b * ATT + a] = cN;
    v[b * ATT + a] = hN + dp[(size_t)b * ATT + a] + dp[(size_t)(32 + b) * ATT + a];
  }
}

// ---------------------------------------------------------------------------
// K3 v13 = r28 + 2-deep A prefetch: at iter ks, STORE the A-regs loaded at
// iter ks-2 (never stalls) and ISSUE loads for ks+2. Unrolled x2 for static
// register naming (La/Lb). LDS dbuf hazard-safe via barrier(ks-1).
__global__ __launch_bounds__(256, 4) void k_score_mfma(const float* __restrict__ enc,
                                                       const unsigned short* __restrict__ WTF,
                                                       const float* __restrict__ b_enc,
                                                       const float* __restrict__ W_g,
                                                       const float* __restrict__ v,
                                                       const int* __restrict__ lens,
                                                       float* __restrict__ ep) {
  const int i = blockIdx.x;                  // 2048 physical blocks
  const int na = (i >> 3) & 1;               // i and i+8: same XCD, na=0/1
  const int tile = (i & 7) | ((i >> 4) << 3);
  const int tt = tile & 31;
  const int b  = tile >> 5;
  const int t0 = tt * 64;
  if (t0 >= lens[b]) return;
  const int tid = threadIdx.x;
  const int lane = tid & 63, wn = tid >> 6;
  const int l15 = lane & 15, l4 = lane >> 4;

  __shared__ unsigned short sA[2][64][40];   // 2 x (64t x 32e), stride 80B
  __shared__ float red[64][4];

  const int rowS = tid >> 2, qS = tid & 3;
  const float* pAg = enc + ((size_t)b * TT_ALL + t0 + rowS) * EPROJS + qS * 8;
  const int r16b = na * 16 + wn * 4;
  const unsigned short* pBf = WTF + (size_t)r16b * 32 * 512 + (size_t)lane * 8;

  f32x4 acc[4][4];
#pragma unroll
  for (int m = 0; m < 4; ++m)
#pragma unroll
    for (int n = 0; n < 4; ++n) acc[m][n] = (f32x4){0.f, 0.f, 0.f, 0.f};

  // 2-deep A prefetch registers
  float4 La0 = *reinterpret_cast<const float4*>(pAg);          // A(0)
  float4 La1 = *reinterpret_cast<const float4*>(pAg + 4);
  float4 Lb0 = *reinterpret_cast<const float4*>(pAg + 32);     // A(1)
  float4 Lb1 = *reinterpret_cast<const float4*>(pAg + 36);

  for (int ks2 = 0; ks2 < 32; ks2 += 2) {
    // ---- even iter: ks = ks2, buf 0 ----
    *reinterpret_cast<short8*>(&sA[0][rowS][qS * 8]) = pack_bf16x8(La0, La1);
    __syncthreads();
    {
      const int kn = (ks2 + 2 < 32) ? ks2 + 2 : 31;            // clamp: wasted, safe
      La0 = *reinterpret_cast<const float4*>(pAg + kn * 32);
      La1 = *reinterpret_cast<const float4*>(pAg + kn * 32 + 4);
    }
    {
      short8 bfr[4];
#pragma unroll
      for (int n = 0; n < 4; ++n)
        bfr[n] = *reinterpret_cast<const short8*>(pBf + (size_t)(n * 32 + ks2) * 512);
      short8 af[4];
#pragma unroll
      for (int m = 0; m < 4; ++m)
        af[m] = *reinterpret_cast<const short8*>(&sA[0][16 * m + l15][l4 * 8]);
#pragma unroll
      for (int n = 0; n < 4; ++n)
#pragma unroll
        for (int m = 0; m < 4; ++m)
          acc[m][n] = __builtin_amdgcn_mfma_f32_16x16x32_bf16(af[m], bfr[n], acc[m][n], 0, 0, 0);
    }
    // ---- odd iter: ks = ks2+1, buf 1 ----
    *reinterpret_cast<short8*>(&sA[1][rowS][qS * 8]) = pack_bf16x8(Lb0, Lb1);
    __syncthreads();
    {
      const int kn = (ks2 + 3 < 32) ? ks2 + 3 : 31;
      Lb0 = *reinterpret_cast<const float4*>(pAg + kn * 32);
      Lb1 = *reinterpret_cast<const float4*>(pAg + kn * 32 + 4);
    }
    {
      short8 bfr[4];
#pragma unroll
      for (int n = 0; n < 4; ++n)
        bfr[n] = *reinterpret_cast<const short8*>(pBf + (size_t)(n * 32 + ks2 + 1) * 512);
      short8 af[4];
#pragma unroll
      for (int m = 0; m < 4; ++m)
        af[m] = *reinterpret_cast<const short8*>(&sA[1][16 * m + l15][l4 * 8]);
#pragma unroll
      for (int n = 0; n < 4; ++n)
#pragma unroll
        for (int m = 0; m < 4; ++m)
          acc[m][n] = __builtin_amdgcn_mfma_f32_16x16x32_bf16(af[m], bfr[n], acc[m][n], 0, 0, 0);
    }
  }

  // epilogue: tanh + W_g over this block's 256 a (D: col=l15 -> a, row=l4*4+j)
  float rp[4][4];
#pragma unroll
  for (int m = 0; m < 4; ++m)
#pragma unroll
    for (int j = 0; j < 4; ++j) rp[m][j] = 0.f;
#pragma unroll
  for (int n = 0; n < 4; ++n) {
    const int a = na * 256 + wn * 64 + 16 * n + l15;
    const float va = v[b * ATT + a] + b_enc[a];
    const float wg = W_g[a];
#pragma unroll
    for (int m = 0; m < 4; ++m)
#pragma unroll
      for (int j = 0; j < 4; ++j) {
        const float x = acc[m][n][j] + va;
        const float th = 1.f - 2.f / (__expf(2.f * x) + 1.f);
        rp[m][j] = fmaf(th, wg, rp[m][j]);
      }
  }
#pragma unroll
  for (int m = 0; m < 4; ++m)
#pragma unroll
    for (int j = 0; j < 4; ++j) {
      float s = rp[m][j];
      s += __shfl_xor(s, 1, 64);
      s += __shfl_xor(s, 2, 64);
      s += __shfl_xor(s, 4, 64);
      s += __shfl_xor(s, 8, 64);
      rp[m][j] = s;
    }
  __syncthreads();
  if (l15 == 0) {
#pragma unroll
    for (int m = 0; m < 4; ++m)
#pragma unroll
      for (int j = 0; j < 4; ++j)
        red[16 * m + l4 * 4 + j][wn] = rp[m][j];
  }
  __syncthreads();
  if (tid < 64) {
    const float s = red[tid][0] + red[tid][1] + red[tid][2] + red[tid][3];
    ep[(size_t)na * (BB * TT_ALL) + b * TT_ALL + t0 + tid] = s;
  }
}

// ---------------------------------------------------------------------------
// K4: masked softmax over 2*(ep0+ep1)  (b_g cancels in softmax)
__global__ __launch_bounds__(256) void k_softmax(const float* __restrict__ ep,
                                                 const int* __restrict__ lens,
                                                 float* __restrict__ wf,
                                                 float* __restrict__ out) {
  const int b = blockIdx.x, tid = threadIdx.x, len = lens[b];
  __shared__ float sbuf[4];
  float vals[8];
  float m = -1e30f;
#pragma unroll
  for (int i = 0; i < 8; ++i) {
    const int t = tid + i * 256;
    const float x = (t < len)
        ? ep[b * TT_ALL + t] + ep[(size_t)BB * TT_ALL + b * TT_ALL + t] : -1e30f;
    vals[i] = x;
    m = fmaxf(m, x);
  }
  for (int off = 32; off; off >>= 1) m = fmaxf(m, __shfl_xor(m, off, 64));
  if ((tid & 63) == 0) sbuf[tid >> 6] = m;
  __syncthreads();
  m = fmaxf(fmaxf(sbuf[0], sbuf[1]), fmaxf(sbuf[2], sbuf[3]));
  __syncthreads();
  float s = 0.f;
#pragma unroll
  for (int i = 0; i < 8; ++i) {
    const int t = tid + i * 256;
    const float p = (t < len) ? expf(2.f * (vals[i] - m)) : 0.f;
    vals[i] = p;
    s += p;
  }
  for (int off = 32; off; off >>= 1) s += __shfl_xor(s, off, 64);
  if ((tid & 63) == 0) sbuf[tid >> 6] = s;
  __syncthreads();
  s = sbuf[0] + sbuf[1] + sbuf[2] + sbuf[3];
  const float inv = 1.f / s;
#pragma unroll
  for (int i = 0; i < 8; ++i) {
    const int t = tid + i * 256;
    const float wv = vals[i] * inv;
    wf[b * TT_ALL + t] = wv;
    out[OFF_W + b * TT_ALL + t] = wv;
  }
}

// ---------------------------------------------------------------------------
// K5/K6: context partials + combine
__global__ __launch_bounds__(256) void k_ctx(const float* __restrict__ enc,
                                             const float* __restrict__ wf,
                                             const int* __restrict__ lens,
                                             float* __restrict__ part) {
  const int blk = blockIdx.x;
  const int b  = blk >> 5;
  const int et = (blk >> 3) & 3;
  const int tc = blk & 7;
  const int tid = threadIdx.x;
  const int e = et * 256 + tid;
  const int len = lens[b];
  const int tbeg = tc * 256;
  const int tend = min(tbeg + 256, len);
  float a0 = 0.f, a1 = 0.f;
  int t = tbeg;
  for (; t + 2 <= tend; t += 2) {
    a0 = fmaf(wf[b * TT_ALL + t + 0], enc[((size_t)b * TT_ALL + t + 0) * EPROJS + e], a0);
    a1 = fmaf(wf[b * TT_ALL + t + 1], enc[((size_t)b * TT_ALL + t + 1) * EPROJS + e], a1);
  }
  for (; t < tend; ++t)
    a0 = fmaf(wf[b * TT_ALL + t], enc[((size_t)b * TT_ALL + t) * EPROJS + e], a0);
  part[((size_t)b * 8 + tc) * EPROJS + e] = a0 + a1;
}

__global__ __launch_bounds__(256) void k_comb(const float* __restrict__ part,
                                              float* __restrict__ out) {
  const int b = blockIdx.x >> 2, et = blockIdx.x & 3;
  const int e = et * 256 + threadIdx.x;
  float s = 0.f;
#pragma unroll
  for (int tc = 0; tc < 8; ++tc) s += part[((size_t)b * 8 + tc) * EPROJS + e];
  out[OFF_C + b * EPROJS + e] = s;
}

// ---------------------------------------------------------------------------
extern "C" void kernel_launch(void* const* d_in, const int* in_sizes, int n_in,
                              void* d_out, int out_size, void* d_ws, size_t ws_size,
                              hipStream_t stream) {
  const float* enc      = (const float*)d_in[0];
  const int*   lens     = (const int*)d_in[1];
  const float* dec_z    = (const float*)d_in[2];
  const float* att_prev = (const float*)d_in[3];
  const float* att_h    = (const float*)d_in[4];
  const float* att_c    = (const float*)d_in[5];
  const float* W_enc    = (const float*)d_in[6];
  const float* b_enc    = (const float*)d_in[7];
  const float* W_dec    = (const float*)d_in[8];
  const float* W_conv   = (const float*)d_in[9];
  const float* W_ih     = (const float*)d_in[10];
  const float* W_hh     = (const float*)d_in[11];
  const float* W_g      = (const float*)d_in[12];
  const float* b_g      = (const float*)d_in[13];
  (void)b_g;  // cancels inside softmax
  float* out = (float*)d_out;
  float* ws  = (float*)d_ws;

  float* cf   = ws + WS_CF;
  float* v    = ws + WS_V;
  float* ep   = ws + WS_EP;
  float* wf   = ws + WS_WF;
  unsigned short* wtf = (unsigned short*)(ws + WS_WT);
  float* part = ws + WS_PART;
  float* gp   = ws + WS_GP;
  float* dp   = ws + WS_DP;

  k_wprepF    <<<32 * 32, 64, 0, stream>>>(W_enc, wtf);
  k_conv      <<<BB * CH, 256, 0, stream>>>(att_prev, W_conv, cf);
  k_gates     <<<64, 256, 0, stream>>>(att_h, W_hh, gp);
  k_dec       <<<16, 256, 0, stream>>>(dec_z, W_dec, dp);
  k_lstm_v    <<<BB, 256, 0, stream>>>(gp, dp, cf, W_ih, att_c, v, out);
  k_score_mfma<<<BB * 32 * 2, 256, 0, stream>>>(enc, wtf, b_enc, W_g, v, lens, ep);
  k_softmax   <<<BB, 256, 0, stream>>>(ep, lens, wf, out);
  k_ctx       <<<BB * 32, 256, 0, stream>>>(enc, wf, lens, part);
  k_comb      <<<BB * 4, 256, 0, stream>>>(part, out);
}

// Round 30
// 225.848 us; speedup vs baseline: 1.3365x; 1.3365x over previous
//
#include <hip/hip_runtime.h>
#include <hip/hip_bf16.h>
#include <cstddef>

#define BB      32
#define TT_ALL  2048
#define EPROJS  1024
#define DUNITS  1024
#define ATT     512
#define CH      10
#define KS      201
#define FILT    100

// Output chunks (FP32): c | w | h_new | c_new
#define OFF_C   0
#define OFF_W   (BB*EPROJS)
#define OFF_H   (OFF_W + BB*TT_ALL)
#define OFF_CN  (OFF_H + BB*ATT)

// ws layout (float offsets)
#define WS_CF    0
#define WS_V     512
#define WS_EP    16896                 // e partials: 2 x 65536
#define WS_WF    147968                // w fp32: 65536
#define WS_WT    213504                // WTF bf16 (512x1024) = 262144 f32 slots
#define WS_PART  475648                // ctx partials: 262144
#define WS_GP    737792                // gates partials: 131072
#define WS_DP    868864                // dec partials: 32768

typedef __attribute__((ext_vector_type(8))) short short8;
typedef __attribute__((ext_vector_type(4))) float f32x4;

__device__ __forceinline__ float sigm(float x) { return 1.f / (1.f + expf(-x)); }
__device__ __forceinline__ unsigned short f2bf(float f) {
  unsigned u = __float_as_uint(f);
  return (unsigned short)((u + 0x7FFFu + ((u >> 16) & 1u)) >> 16);  // RNE
}
__device__ __forceinline__ ushort2 f2bf2(float a, float b) {
  __hip_bfloat162 h = __float22bfloat162_rn(float2{a, b});
  return *reinterpret_cast<ushort2*>(&h);
}
__device__ __forceinline__ short8 pack_bf16x8(const float4 a, const float4 b) {
  union { short8 s; ushort2 u[4]; } r;
  r.u[0] = f2bf2(a.x, a.y); r.u[1] = f2bf2(a.z, a.w);
  r.u[2] = f2bf2(b.x, b.y); r.u[3] = f2bf2(b.z, b.w);
  return r.s;
}

// ---------------------------------------------------------------------------
// K0: W_enc (E,A) fp32 -> WTF fragment-major bf16 (B-operand).
__global__ __launch_bounds__(64) void k_wprepF(const float* __restrict__ W,
                                               unsigned short* __restrict__ WTF) {
  const int r16 = blockIdx.x >> 5, ks = blockIdx.x & 31;
  const int l = threadIdx.x;
  const int a = r16 * 16 + (l & 15);
  const int e0 = ks * 32 + (l >> 4) * 8;
  union { short8 s; unsigned short h[8]; } r;
#pragma unroll
  for (int j = 0; j < 8; ++j) r.h[j] = f2bf(W[(size_t)(e0 + j) * ATT + a]);
  *reinterpret_cast<short8*>(&WTF[((size_t)(r16 * 32 + ks) * 64 + l) * 8]) = r.s;
}

// ---------------------------------------------------------------------------
// K1: location conv -> relu -> max over T
__global__ __launch_bounds__(256) void k_conv(const float* __restrict__ att_prev,
                                              const float* __restrict__ W_conv,
                                              float* __restrict__ conv_feat) {
  const int b  = blockIdx.x / CH;
  const int ch = blockIdx.x % CH;
  __shared__ float sprev[TT_ALL + 2 * FILT];
  __shared__ float sw[KS];
  __shared__ float red[4];
  const int tid = threadIdx.x;
  for (int i = tid; i < TT_ALL + 2 * FILT; i += 256) {
    int t = i - FILT;
    sprev[i] = (t >= 0 && t < TT_ALL) ? att_prev[b * TT_ALL + t] : 0.f;
  }
  for (int i = tid; i < KS; i += 256) sw[i] = W_conv[ch * KS + i];
  __syncthreads();
  float m = 0.f;
  for (int t = tid; t < TT_ALL; t += 256) {
    float s = 0.f;
    for (int k = 0; k < KS; ++k) s = fmaf(sprev[t + k], sw[k], s);
    m = fmaxf(m, s);
  }
  for (int off = 32; off; off >>= 1) m = fmaxf(m, __shfl_xor(m, off, 64));
  if ((tid & 63) == 0) red[tid >> 6] = m;
  __syncthreads();
  if (tid == 0)
    conv_feat[b * CH + ch] = fmaxf(fmaxf(red[0], red[1]), fmaxf(red[2], red[3]));
}

// ---------------------------------------------------------------------------
// K2a: gates partial
__global__ __launch_bounds__(256) void k_gates(const float* __restrict__ att_h,
                                               const float* __restrict__ W_hh,
                                               float* __restrict__ gp) {
  const int jt = blockIdx.x >> 1;
  const int sp = blockIdx.x & 1;
  const int j0 = jt * 64;
  const int k0 = sp * 256;
  const int tid = threadIdx.x;
  const int al = tid & 63, bg = tid >> 6;
  __shared__ float sW[64][65];
  __shared__ float sH[32][64];
  float acc[8];
#pragma unroll
  for (int i = 0; i < 8; ++i) acc[i] = 0.f;
  for (int kc = 0; kc < 256; kc += 64) {
    __syncthreads();
#pragma unroll
    for (int i = 0; i < 4; ++i) {
      const int f = tid + i * 256;
      const int r = f >> 4, q = f & 15;
      const float4 w4 = *reinterpret_cast<const float4*>(
          &W_hh[(size_t)(j0 + r) * ATT + k0 + kc + q * 4]);
      sW[r][q * 4 + 0] = w4.x; sW[r][q * 4 + 1] = w4.y;
      sW[r][q * 4 + 2] = w4.z; sW[r][q * 4 + 3] = w4.w;
    }
#pragma unroll
    for (int i = 0; i < 2; ++i) {
      const int g = tid + i * 256;
      const int r = g >> 4, q = g & 15;
      *reinterpret_cast<float4*>(&sH[r][q * 4]) = *reinterpret_cast<const float4*>(
          &att_h[(size_t)r * ATT + k0 + kc + q * 4]);
    }
    __syncthreads();
#pragma unroll 16
    for (int k = 0; k < 64; ++k) {
      const float w = sW[al][k];
#pragma unroll
      for (int bb = 0; bb < 8; ++bb)
        acc[bb] = fmaf(w, sH[bg * 8 + bb][k], acc[bb]);
    }
  }
#pragma unroll
  for (int bb = 0; bb < 8; ++bb)
    gp[((size_t)(sp * 32 + bg * 8 + bb)) * (4 * ATT) + j0 + al] = acc[bb];
}

// ---------------------------------------------------------------------------
// K2b: dec partial
__global__ __launch_bounds__(256) void k_dec(const float* __restrict__ dec_z,
                                             const float* __restrict__ W_dec,
                                             float* __restrict__ dp) {
  const int at = blockIdx.x >> 1;
  const int sp = blockIdx.x & 1;
  const int a0 = at * 64;
  const int d0 = sp * 512;
  const int tid = threadIdx.x;
  const int al = tid & 63, bg = tid >> 6;
  __shared__ float sW[64][64];
  __shared__ float sZ[32][64];
  float acc[8];
#pragma unroll
  for (int i = 0; i < 8; ++i) acc[i] = 0.f;
  for (int dc = 0; dc < 512; dc += 64) {
    __syncthreads();
#pragma unroll
    for (int i = 0; i < 4; ++i) {
      const int f = tid + i * 256;
      const int r = f >> 4, q = f & 15;
      *reinterpret_cast<float4*>(&sW[r][q * 4]) = *reinterpret_cast<const float4*>(
          &W_dec[(size_t)(d0 + dc + r) * ATT + a0 + q * 4]);
    }
#pragma unroll
    for (int i = 0; i < 2; ++i) {
      const int g = tid + i * 256;
      const int r = g >> 4, q = g & 15;
      *reinterpret_cast<float4*>(&sZ[r][q * 4]) = *reinterpret_cast<const float4*>(
          &dec_z[(size_t)r * DUNITS + d0 + dc + q * 4]);
    }
    __syncthreads();
#pragma unroll 16
    for (int d = 0; d < 64; ++d) {
      const float w = sW[d][al];
#pragma unroll
      for (int bb = 0; bb < 8; ++bb)
        acc[bb] = fmaf(sZ[bg * 8 + bb][d], w, acc[bb]);
    }
  }
#pragma unroll
  for (int bb = 0; bb < 8; ++bb)
    dp[((size_t)(sp * 32 + bg * 8 + bb)) * ATT + a0 + al] = acc[bb];
}

// ---------------------------------------------------------------------------
// K2c: combine + LSTM + v
__global__ __launch_bounds__(256) void k_lstm_v(const float* __restrict__ gp,
                                                const float* __restrict__ dp,
                                                const float* __restrict__ conv_feat,
                                                const float* __restrict__ W_ih,
                                                const float* __restrict__ att_c,
                                                float* __restrict__ v,
                                                float* __restrict__ out) {
  const int b = blockIdx.x, tid = threadIdx.x;
  __shared__ float scf[CH];
  if (tid < CH) scf[tid] = conv_feat[b * CH + tid];
  __syncthreads();
  for (int a = tid; a < ATT; a += 256) {
    float g4[4];
#pragma unroll
    for (int q = 0; q < 4; ++q) {
      const int j = q * ATT + a;
      float g = gp[(size_t)b * (4 * ATT) + j] + gp[(size_t)(32 + b) * (4 * ATT) + j];
#pragma unroll
      for (int c = 0; c < CH; ++c) g = fmaf(scf[c], W_ih[(size_t)j * CH + c], g);
      g4[q] = g;
    }
    const float ig = sigm(g4[0]);
    const float fg = sigm(g4[1]);
    const float gg = tanhf(g4[2]);
    const float og = sigm(g4[3]);
    const float cN = fg * att_c[b * ATT + a] + ig * gg;
    const float hN = og * tanhf(cN);
    out[OFF_H + b * ATT + a]  = hN;
    out[OFF_CN + b * ATT + a] = cN;
    v[b * ATT + a] = hN + dp[(size_t)b * ATT + a] + dp[(size_t)(32 + b) * ATT + a];
  }
}

// ---------------------------------------------------------------------------
// K3 v14 = r28 base, 64e per iteration (2 k-substeps per barrier, 16 iters).
// Block = 64t x 256a (4 waves of 64x64), pair-swizzled na split; 1-deep prefetch.
__global__ __launch_bounds__(256, 4) void k_score_mfma(const float* __restrict__ enc,
                                                       const unsigned short* __restrict__ WTF,
                                                       const float* __restrict__ b_enc,
                                                       const float* __restrict__ W_g,
                                                       const float* __restrict__ v,
                                                       const int* __restrict__ lens,
                                                       float* __restrict__ ep) {
  const int i = blockIdx.x;                  // 2048 physical blocks
  const int na = (i >> 3) & 1;               // i and i+8: same XCD, na=0/1
  const int tile = (i & 7) | ((i >> 4) << 3);
  const int tt = tile & 31;
  const int b  = tile >> 5;
  const int t0 = tt * 64;
  if (t0 >= lens[b]) return;
  const int tid = threadIdx.x;
  const int lane = tid & 63, wn = tid >> 6;
  const int l15 = lane & 15, l4 = lane >> 4;

  __shared__ unsigned short sA[2][2][64][40];  // [buf][half][row][32e+pad]
  __shared__ float red[64][4];

  const int rowS = tid >> 2, qS = tid & 3;     // 4 thr/row, 16 floats each
  const int hS = qS >> 1, cS = (qS & 1) * 16;  // half, col within half
  const float* pAg = enc + ((size_t)b * TT_ALL + t0 + rowS) * EPROJS + qS * 16;
  const int r16b = na * 16 + wn * 4;
  const unsigned short* pBf = WTF + (size_t)r16b * 32 * 512 + (size_t)lane * 8;

  f32x4 acc[4][4];
#pragma unroll
  for (int m = 0; m < 4; ++m)
#pragma unroll
    for (int n = 0; n < 4; ++n) acc[m][n] = (f32x4){0.f, 0.f, 0.f, 0.f};

  float4 L0 = *reinterpret_cast<const float4*>(pAg + 0);
  float4 L1 = *reinterpret_cast<const float4*>(pAg + 4);
  float4 L2 = *reinterpret_cast<const float4*>(pAg + 8);
  float4 L3 = *reinterpret_cast<const float4*>(pAg + 12);

  for (int it = 0; it < 16; ++it) {
    const int buf = it & 1;
    *reinterpret_cast<short8*>(&sA[buf][hS][rowS][cS + 0]) = pack_bf16x8(L0, L1);
    *reinterpret_cast<short8*>(&sA[buf][hS][rowS][cS + 8]) = pack_bf16x8(L2, L3);
    __syncthreads();
    if (it + 1 < 16) {
      const float* p = pAg + (it + 1) * 64;
      L0 = *reinterpret_cast<const float4*>(p + 0);
      L1 = *reinterpret_cast<const float4*>(p + 4);
      L2 = *reinterpret_cast<const float4*>(p + 8);
      L3 = *reinterpret_cast<const float4*>(p + 12);
    }
#pragma unroll
    for (int kk2 = 0; kk2 < 2; ++kk2) {
      const int ks = it * 2 + kk2;
      short8 bfr[4];
#pragma unroll
      for (int n = 0; n < 4; ++n)
        bfr[n] = *reinterpret_cast<const short8*>(pBf + (size_t)(n * 32 + ks) * 512);
      short8 af[4];
#pragma unroll
      for (int m = 0; m < 4; ++m)
        af[m] = *reinterpret_cast<const short8*>(&sA[buf][kk2][16 * m + l15][l4 * 8]);
#pragma unroll
      for (int n = 0; n < 4; ++n)
#pragma unroll
        for (int m = 0; m < 4; ++m)
          acc[m][n] = __builtin_amdgcn_mfma_f32_16x16x32_bf16(af[m], bfr[n], acc[m][n], 0, 0, 0);
    }
  }

  // epilogue: tanh + W_g over this block's 256 a (D: col=l15 -> a, row=l4*4+j)
  float rp[4][4];
#pragma unroll
  for (int m = 0; m < 4; ++m)
#pragma unroll
    for (int j = 0; j < 4; ++j) rp[m][j] = 0.f;
#pragma unroll
  for (int n = 0; n < 4; ++n) {
    const int a = na * 256 + wn * 64 + 16 * n + l15;
    const float va = v[b * ATT + a] + b_enc[a];
    const float wg = W_g[a];
#pragma unroll
    for (int m = 0; m < 4; ++m)
#pragma unroll
      for (int j = 0; j < 4; ++j) {
        const float x = acc[m][n][j] + va;
        const float th = 1.f - 2.f / (__expf(2.f * x) + 1.f);
        rp[m][j] = fmaf(th, wg, rp[m][j]);
      }
  }
#pragma unroll
  for (int m = 0; m < 4; ++m)
#pragma unroll
    for (int j = 0; j < 4; ++j) {
      float s = rp[m][j];
      s += __shfl_xor(s, 1, 64);
      s += __shfl_xor(s, 2, 64);
      s += __shfl_xor(s, 4, 64);
      s += __shfl_xor(s, 8, 64);
      rp[m][j] = s;
    }
  __syncthreads();
  if (l15 == 0) {
#pragma unroll
    for (int m = 0; m < 4; ++m)
#pragma unroll
      for (int j = 0; j < 4; ++j)
        red[16 * m + l4 * 4 + j][wn] = rp[m][j];
  }
  __syncthreads();
  if (tid < 64) {
    const float s = red[tid][0] + red[tid][1] + red[tid][2] + red[tid][3];
    ep[(size_t)na * (BB * TT_ALL) + b * TT_ALL + t0 + tid] = s;
  }
}

// ---------------------------------------------------------------------------
// K4: masked softmax over 2*(ep0+ep1)  (b_g cancels in softmax)
__global__ __launch_bounds__(256) void k_softmax(const float* __restrict__ ep,
                                                 const int* __restrict__ lens,
                                                 float* __restrict__ wf,
                                                 float* __restrict__ out) {
  const int b = blockIdx.x, tid = threadIdx.x, len = lens[b];
  __shared__ float sbuf[4];
  float vals[8];
  float m = -1e30f;
#pragma unroll
  for (int i = 0; i < 8; ++i) {
    const int t = tid + i * 256;
    const float x = (t < len)
        ? ep[b * TT_ALL + t] + ep[(size_t)BB * TT_ALL + b * TT_ALL + t] : -1e30f;
    vals[i] = x;
    m = fmaxf(m, x);
  }
  for (int off = 32; off; off >>= 1) m = fmaxf(m, __shfl_xor(m, off, 64));
  if ((tid & 63) == 0) sbuf[tid >> 6] = m;
  __syncthreads();
  m = fmaxf(fmaxf(sbuf[0], sbuf[1]), fmaxf(sbuf[2], sbuf[3]));
  __syncthreads();
  float s = 0.f;
#pragma unroll
  for (int i = 0; i < 8; ++i) {
    const int t = tid + i * 256;
    const float p = (t < len) ? expf(2.f * (vals[i] - m)) : 0.f;
    vals[i] = p;
    s += p;
  }
  for (int off = 32; off; off >>= 1) s += __shfl_xor(s, off, 64);
  if ((tid & 63) == 0) sbuf[tid >> 6] = s;
  __syncthreads();
  s = sbuf[0] + sbuf[1] + sbuf[2] + sbuf[3];
  const float inv = 1.f / s;
#pragma unroll
  for (int i = 0; i < 8; ++i) {
    const int t = tid + i * 256;
    const float wv = vals[i] * inv;
    wf[b * TT_ALL + t] = wv;
    out[OFF_W + b * TT_ALL + t] = wv;
  }
}

// ---------------------------------------------------------------------------
// K5/K6: context partials + combine
__global__ __launch_bounds__(256) void k_ctx(const float* __restrict__ enc,
                                             const float* __restrict__ wf,
                                             const int* __restrict__ lens,
                                             float* __restrict__ part) {
  const int blk = blockIdx.x;
  const int b  = blk >> 5;
  const int et = (blk >> 3) & 3;
  const int tc = blk & 7;
  const int tid = threadIdx.x;
  const int e = et * 256 + tid;
  const int len = lens[b];
  const int tbeg = tc * 256;
  const int tend = min(tbeg + 256, len);
  float a0 = 0.f, a1 = 0.f;
  int t = tbeg;
  for (; t + 2 <= tend; t += 2) {
    a0 = fmaf(wf[b * TT_ALL + t + 0], enc[((size_t)b * TT_ALL + t + 0) * EPROJS + e], a0);
    a1 = fmaf(wf[b * TT_ALL + t + 1], enc[((size_t)b * TT_ALL + t + 1) * EPROJS + e], a1);
  }
  for (; t < tend; ++t)
    a0 = fmaf(wf[b * TT_ALL + t], enc[((size_t)b * TT_ALL + t) * EPROJS + e], a0);
  part[((size_t)b * 8 + tc) * EPROJS + e] = a0 + a1;
}

__global__ __launch_bounds__(256) void k_comb(const float* __restrict__ part,
                                              float* __restrict__ out) {
  const int b = blockIdx.x >> 2, et = blockIdx.x & 3;
  const int e = et * 256 + threadIdx.x;
  float s = 0.f;
#pragma unroll
  for (int tc = 0; tc < 8; ++tc) s += part[((size_t)b * 8 + tc) * EPROJS + e];
  out[OFF_C + b * EPROJS + e] = s;
}

// ---------------------------------------------------------------------------
extern "C" void kernel_launch(void* const* d_in, const int* in_sizes, int n_in,
                              void* d_out, int out_size, void* d_ws, size_t ws_size,
                              hipStream_t stream) {
  const float* enc      = (const float*)d_in[0];
  const int*   lens     = (const int*)d_in[1];
  const float* dec_z    = (const float*)d_in[2];
  const float* att_prev = (const float*)d_in[3];
  const float* att_h    = (const float*)d_in[4];
  const float* att_c    = (const float*)d_in[5];
  const float* W_enc    = (const float*)d_in[6];
  const float* b_enc    = (const float*)d_in[7];
  const float* W_dec    = (const float*)d_in[8];
  const float* W_conv   = (const float*)d_in[9];
  const float* W_ih     = (const float*)d_in[10];
  const float* W_hh     = (const float*)d_in[11];
  const float* W_g      = (const float*)d_in[12];
  const float* b_g      = (const float*)d_in[13];
  (void)b_g;  // cancels inside softmax
  float* out = (float*)d_out;
  float* ws  = (float*)d_ws;

  float* cf   = ws + WS_CF;
  float* v    = ws + WS_V;
  float* ep   = ws + WS_EP;
  float* wf   = ws + WS_WF;
  unsigned short* wtf = (unsigned short*)(ws + WS_WT);
  float* part = ws + WS_PART;
  float* gp   = ws + WS_GP;
  float* dp   = ws + WS_DP;

  k_wprepF    <<<32 * 32, 64, 0, stream>>>(W_enc, wtf);
  k_conv      <<<BB * CH, 256, 0, stream>>>(att_prev, W_conv, cf);
  k_gates     <<<64, 256, 0, stream>>>(att_h, W_hh, gp);
  k_dec       <<<16, 256, 0, stream>>>(dec_z, W_dec, dp);
  k_lstm_v    <<<BB, 256, 0, stream>>>(gp, dp, cf, W_ih, att_c, v, out);
  k_score_mfma<<<BB * 32 * 2, 256, 0, stream>>>(enc, wtf, b_enc, W_g, v, lens, ep);
  k_softmax   <<<BB, 256, 0, stream>>>(ep, lens, wf, out);
  k_ctx       <<<BB * 32, 256, 0, stream>>>(enc, wf, lens, part);
  k_comb      <<<BB * 4, 256, 0, stream>>>(part, out);
}

// Round 31
// 224.143 us; speedup vs baseline: 1.3467x; 1.0076x over previous
//
#include <hip/hip_runtime.h>
#include <hip/hip_bf16.h>
#include <cstddef>

#define BB      32
#define TT_ALL  2048
#define EPROJS  1024
#define DUNITS  1024
#define ATT     512
#define CH      10
#define KS      201
#define FILT    100

// Output chunks (FP32): c | w | h_new | c_new
#define OFF_C   0
#define OFF_W   (BB*EPROJS)
#define OFF_H   (OFF_W + BB*TT_ALL)
#define OFF_CN  (OFF_H + BB*ATT)

// ws layout (float offsets)
#define WS_CF    0
#define WS_V     512
#define WS_EP    16896                 // e partials: 2 x 65536
#define WS_WF    147968                // w fp32: 65536
#define WS_WT    213504                // WTF bf16 (512x1024) = 262144 f32 slots
#define WS_PART  475648                // ctx partials: 262144
#define WS_GP    737792                // gates partials: 131072
#define WS_DP    868864                // dec partials: 32768

typedef __attribute__((ext_vector_type(8))) short short8;
typedef __attribute__((ext_vector_type(4))) float f32x4;

__device__ __forceinline__ float sigm(float x) { return 1.f / (1.f + expf(-x)); }
__device__ __forceinline__ unsigned short f2bf(float f) {
  unsigned u = __float_as_uint(f);
  return (unsigned short)((u + 0x7FFFu + ((u >> 16) & 1u)) >> 16);  // RNE
}
__device__ __forceinline__ ushort2 f2bf2(float a, float b) {
  __hip_bfloat162 h = __float22bfloat162_rn(float2{a, b});
  return *reinterpret_cast<ushort2*>(&h);
}
__device__ __forceinline__ short8 pack_bf16x8(const float4 a, const float4 b) {
  union { short8 s; ushort2 u[4]; } r;
  r.u[0] = f2bf2(a.x, a.y); r.u[1] = f2bf2(a.z, a.w);
  r.u[2] = f2bf2(b.x, b.y); r.u[3] = f2bf2(b.z, b.w);
  return r.s;
}

// ---------------------------------------------------------------------------
// K0: W_enc (E,A) fp32 -> WTF fragment-major bf16 (B-operand).
__global__ __launch_bounds__(64) void k_wprepF(const float* __restrict__ W,
                                               unsigned short* __restrict__ WTF) {
  const int r16 = blockIdx.x >> 5, ks = blockIdx.x & 31;
  const int l = threadIdx.x;
  const int a = r16 * 16 + (l & 15);
  const int e0 = ks * 32 + (l >> 4) * 8;
  union { short8 s; unsigned short h[8]; } r;
#pragma unroll
  for (int j = 0; j < 8; ++j) r.h[j] = f2bf(W[(size_t)(e0 + j) * ATT + a]);
  *reinterpret_cast<short8*>(&WTF[((size_t)(r16 * 32 + ks) * 64 + l) * 8]) = r.s;
}

// ---------------------------------------------------------------------------
// K1: location conv -> relu -> max over T
__global__ __launch_bounds__(256) void k_conv(const float* __restrict__ att_prev,
                                              const float* __restrict__ W_conv,
                                              float* __restrict__ conv_feat) {
  const int b  = blockIdx.x / CH;
  const int ch = blockIdx.x % CH;
  __shared__ float sprev[TT_ALL + 2 * FILT];
  __shared__ float sw[KS];
  __shared__ float red[4];
  const int tid = threadIdx.x;
  for (int i = tid; i < TT_ALL + 2 * FILT; i += 256) {
    int t = i - FILT;
    sprev[i] = (t >= 0 && t < TT_ALL) ? att_prev[b * TT_ALL + t] : 0.f;
  }
  for (int i = tid; i < KS; i += 256) sw[i] = W_conv[ch * KS + i];
  __syncthreads();
  float m = 0.f;
  for (int t = tid; t < TT_ALL; t += 256) {
    float s = 0.f;
    for (int k = 0; k < KS; ++k) s = fmaf(sprev[t + k], sw[k], s);
    m = fmaxf(m, s);
  }
  for (int off = 32; off; off >>= 1) m = fmaxf(m, __shfl_xor(m, off, 64));
  if ((tid & 63) == 0) red[tid >> 6] = m;
  __syncthreads();
  if (tid == 0)
    conv_feat[b * CH + ch] = fmaxf(fmaxf(red[0], red[1]), fmaxf(red[2], red[3]));
}

// ---------------------------------------------------------------------------
// K2a: gates partial
__global__ __launch_bounds__(256) void k_gates(const float* __restrict__ att_h,
                                               const float* __restrict__ W_hh,
                                               float* __restrict__ gp) {
  const int jt = blockIdx.x >> 1;
  const int sp = blockIdx.x & 1;
  const int j0 = jt * 64;
  const int k0 = sp * 256;
  const int tid = threadIdx.x;
  const int al = tid & 63, bg = tid >> 6;
  __shared__ float sW[64][65];
  __shared__ float sH[32][64];
  float acc[8];
#pragma unroll
  for (int i = 0; i < 8; ++i) acc[i] = 0.f;
  for (int kc = 0; kc < 256; kc += 64) {
    __syncthreads();
#pragma unroll
    for (int i = 0; i < 4; ++i) {
      const int f = tid + i * 256;
      const int r = f >> 4, q = f & 15;
      const float4 w4 = *reinterpret_cast<const float4*>(
          &W_hh[(size_t)(j0 + r) * ATT + k0 + kc + q * 4]);
      sW[r][q * 4 + 0] = w4.x; sW[r][q * 4 + 1] = w4.y;
      sW[r][q * 4 + 2] = w4.z; sW[r][q * 4 + 3] = w4.w;
    }
#pragma unroll
    for (int i = 0; i < 2; ++i) {
      const int g = tid + i * 256;
      const int r = g >> 4, q = g & 15;
      *reinterpret_cast<float4*>(&sH[r][q * 4]) = *reinterpret_cast<const float4*>(
          &att_h[(size_t)r * ATT + k0 + kc + q * 4]);
    }
    __syncthreads();
#pragma unroll 16
    for (int k = 0; k < 64; ++k) {
      const float w = sW[al][k];
#pragma unroll
      for (int bb = 0; bb < 8; ++bb)
        acc[bb] = fmaf(w, sH[bg * 8 + bb][k], acc[bb]);
    }
  }
#pragma unroll
  for (int bb = 0; bb < 8; ++bb)
    gp[((size_t)(sp * 32 + bg * 8 + bb)) * (4 * ATT) + j0 + al] = acc[bb];
}

// ---------------------------------------------------------------------------
// K2b: dec partial
__global__ __launch_bounds__(256) void k_dec(const float* __restrict__ dec_z,
                                             const float* __restrict__ W_dec,
                                             float* __restrict__ dp) {
  const int at = blockIdx.x >> 1;
  const int sp = blockIdx.x & 1;
  const int a0 = at * 64;
  const int d0 = sp * 512;
  const int tid = threadIdx.x;
  const int al = tid & 63, bg = tid >> 6;
  __shared__ float sW[64][64];
  __shared__ float sZ[32][64];
  float acc[8];
#pragma unroll
  for (int i = 0; i < 8; ++i) acc[i] = 0.f;
  for (int dc = 0; dc < 512; dc += 64) {
    __syncthreads();
#pragma unroll
    for (int i = 0; i < 4; ++i) {
      const int f = tid + i * 256;
      const int r = f >> 4, q = f & 15;
      *reinterpret_cast<float4*>(&sW[r][q * 4]) = *reinterpret_cast<const float4*>(
          &W_dec[(size_t)(d0 + dc + r) * ATT + a0 + q * 4]);
    }
#pragma unroll
    for (int i = 0; i < 2; ++i) {
      const int g = tid + i * 256;
      const int r = g >> 4, q = g & 15;
      *reinterpret_cast<float4*>(&sZ[r][q * 4]) = *reinterpret_cast<const float4*>(
          &dec_z[(size_t)r * DUNITS + d0 + dc + q * 4]);
    }
    __syncthreads();
#pragma unroll 16
    for (int d = 0; d < 64; ++d) {
      const float w = sW[d][al];
#pragma unroll
      for (int bb = 0; bb < 8; ++bb)
        acc[bb] = fmaf(sZ[bg * 8 + bb][d], w, acc[bb]);
    }
  }
#pragma unroll
  for (int bb = 0; bb < 8; ++bb)
    dp[((size_t)(sp * 32 + bg * 8 + bb)) * ATT + a0 + al] = acc[bb];
}

// ---------------------------------------------------------------------------
// K2c: combine + LSTM + v
__global__ __launch_bounds__(256) void k_lstm_v(const float* __restrict__ gp,
                                                const float* __restrict__ dp,
                                                const float* __restrict__ conv_feat,
                                                const float* __restrict__ W_ih,
                                                const float* __restrict__ att_c,
                                                float* __restrict__ v,
                                                float* __restrict__ out) {
  const int b = blockIdx.x, tid = threadIdx.x;
  __shared__ float scf[CH];
  if (tid < CH) scf[tid] = conv_feat[b * CH + tid];
  __syncthreads();
  for (int a = tid; a < ATT; a += 256) {
    float g4[4];
#pragma unroll
    for (int q = 0; q < 4; ++q) {
      const int j = q * ATT + a;
      float g = gp[(size_t)b * (4 * ATT) + j] + gp[(size_t)(32 + b) * (4 * ATT) + j];
#pragma unroll
      for (int c = 0; c < CH; ++c) g = fmaf(scf[c], W_ih[(size_t)j * CH + c], g);
      g4[q] = g;
    }
    const float ig = sigm(g4[0]);
    const float fg = sigm(g4[1]);
    const float gg = tanhf(g4[2]);
    const float og = sigm(g4[3]);
    const float cN = fg * att_c[b * ATT + a] + ig * gg;
    const float hN = og * tanhf(cN);
    out[OFF_H + b * ATT + a]  = hN;
    out[OFF_CN + b * ATT + a] = cN;
    v[b * ATT + a] = hN + dp[(size_t)b * ATT + a] + dp[(size_t)(32 + b) * ATT + a];
  }
}

// ---------------------------------------------------------------------------
// K3 v15 = r28 verbatim + s_setprio(1) around the MFMA cluster (T5).
__global__ __launch_bounds__(256, 4) void k_score_mfma(const float* __restrict__ enc,
                                                       const unsigned short* __restrict__ WTF,
                                                       const float* __restrict__ b_enc,
                                                       const float* __restrict__ W_g,
                                                       const float* __restrict__ v,
                                                       const int* __restrict__ lens,
                                                       float* __restrict__ ep) {
  const int i = blockIdx.x;                  // 2048 physical blocks
  const int na = (i >> 3) & 1;               // i and i+8: same XCD, na=0/1
  const int tile = (i & 7) | ((i >> 4) << 3);
  const int tt = tile & 31;
  const int b  = tile >> 5;
  const int t0 = tt * 64;
  if (t0 >= lens[b]) return;
  const int tid = threadIdx.x;
  const int lane = tid & 63, wn = tid >> 6;
  const int l15 = lane & 15, l4 = lane >> 4;

  __shared__ unsigned short sA[2][64][40];   // 2 x (64t x 32e), stride 80B
  __shared__ float red[64][4];

  const int rowS = tid >> 2, qS = tid & 3;
  const float* pAg = enc + ((size_t)b * TT_ALL + t0 + rowS) * EPROJS + qS * 8;
  const int r16b = na * 16 + wn * 4;
  const unsigned short* pBf = WTF + (size_t)r16b * 32 * 512 + (size_t)lane * 8;

  f32x4 acc[4][4];
#pragma unroll
  for (int m = 0; m < 4; ++m)
#pragma unroll
    for (int n = 0; n < 4; ++n) acc[m][n] = (f32x4){0.f, 0.f, 0.f, 0.f};

  float4 a0 = *reinterpret_cast<const float4*>(pAg);
  float4 a1 = *reinterpret_cast<const float4*>(pAg + 4);

  for (int ks = 0; ks < 32; ++ks) {
    const int buf = ks & 1;
    *reinterpret_cast<short8*>(&sA[buf][rowS][qS * 8]) = pack_bf16x8(a0, a1);
    __syncthreads();
    if (ks + 1 < 32) {
      a0 = *reinterpret_cast<const float4*>(pAg + (ks + 1) * 32);
      a1 = *reinterpret_cast<const float4*>(pAg + (ks + 1) * 32 + 4);
    }
    short8 bfr[4];
#pragma unroll
    for (int n = 0; n < 4; ++n)
      bfr[n] = *reinterpret_cast<const short8*>(pBf + (size_t)(n * 32 + ks) * 512);
    short8 af[4];
#pragma unroll
    for (int m = 0; m < 4; ++m)
      af[m] = *reinterpret_cast<const short8*>(&sA[buf][16 * m + l15][l4 * 8]);
    __builtin_amdgcn_s_setprio(1);
#pragma unroll
    for (int n = 0; n < 4; ++n)
#pragma unroll
      for (int m = 0; m < 4; ++m)
        acc[m][n] = __builtin_amdgcn_mfma_f32_16x16x32_bf16(af[m], bfr[n], acc[m][n], 0, 0, 0);
    __builtin_amdgcn_s_setprio(0);
  }

  // epilogue: tanh + W_g over this block's 256 a (D: col=l15 -> a, row=l4*4+j)
  float rp[4][4];
#pragma unroll
  for (int m = 0; m < 4; ++m)
#pragma unroll
    for (int j = 0; j < 4; ++j) rp[m][j] = 0.f;
#pragma unroll
  for (int n = 0; n < 4; ++n) {
    const int a = na * 256 + wn * 64 + 16 * n + l15;
    const float va = v[b * ATT + a] + b_enc[a];
    const float wg = W_g[a];
#pragma unroll
    for (int m = 0; m < 4; ++m)
#pragma unroll
      for (int j = 0; j < 4; ++j) {
        const float x = acc[m][n][j] + va;
        const float th = 1.f - 2.f / (__expf(2.f * x) + 1.f);
        rp[m][j] = fmaf(th, wg, rp[m][j]);
      }
  }
#pragma unroll
  for (int m = 0; m < 4; ++m)
#pragma unroll
    for (int j = 0; j < 4; ++j) {
      float s = rp[m][j];
      s += __shfl_xor(s, 1, 64);
      s += __shfl_xor(s, 2, 64);
      s += __shfl_xor(s, 4, 64);
      s += __shfl_xor(s, 8, 64);
      rp[m][j] = s;
    }
  __syncthreads();
  if (l15 == 0) {
#pragma unroll
    for (int m = 0; m < 4; ++m)
#pragma unroll
      for (int j = 0; j < 4; ++j)
        red[16 * m + l4 * 4 + j][wn] = rp[m][j];
  }
  __syncthreads();
  if (tid < 64) {
    const float s = red[tid][0] + red[tid][1] + red[tid][2] + red[tid][3];
    ep[(size_t)na * (BB * TT_ALL) + b * TT_ALL + t0 + tid] = s;
  }
}

// ---------------------------------------------------------------------------
// K4: masked softmax over 2*(ep0+ep1)  (b_g cancels in softmax)
__global__ __launch_bounds__(256) void k_softmax(const float* __restrict__ ep,
                                                 const int* __restrict__ lens,
                                                 float* __restrict__ wf,
                                                 float* __restrict__ out) {
  const int b = blockIdx.x, tid = threadIdx.x, len = lens[b];
  __shared__ float sbuf[4];
  float vals[8];
  float m = -1e30f;
#pragma unroll
  for (int i = 0; i < 8; ++i) {
    const int t = tid + i * 256;
    const float x = (t < len)
        ? ep[b * TT_ALL + t] + ep[(size_t)BB * TT_ALL + b * TT_ALL + t] : -1e30f;
    vals[i] = x;
    m = fmaxf(m, x);
  }
  for (int off = 32; off; off >>= 1) m = fmaxf(m, __shfl_xor(m, off, 64));
  if ((tid & 63) == 0) sbuf[tid >> 6] = m;
  __syncthreads();
  m = fmaxf(fmaxf(sbuf[0], sbuf[1]), fmaxf(sbuf[2], sbuf[3]));
  __syncthreads();
  float s = 0.f;
#pragma unroll
  for (int i = 0; i < 8; ++i) {
    const int t = tid + i * 256;
    const float p = (t < len) ? expf(2.f * (vals[i] - m)) : 0.f;
    vals[i] = p;
    s += p;
  }
  for (int off = 32; off; off >>= 1) s += __shfl_xor(s, off, 64);
  if ((tid & 63) == 0) sbuf[tid >> 6] = s;
  __syncthreads();
  s = sbuf[0] + sbuf[1] + sbuf[2] + sbuf[3];
  const float inv = 1.f / s;
#pragma unroll
  for (int i = 0; i < 8; ++i) {
    const int t = tid + i * 256;
    const float wv = vals[i] * inv;
    wf[b * TT_ALL + t] = wv;
    out[OFF_W + b * TT_ALL + t] = wv;
  }
}

// ---------------------------------------------------------------------------
// K5/K6: context partials + combine
__global__ __launch_bounds__(256) void k_ctx(const float* __restrict__ enc,
                                             const float* __restrict__ wf,
                                             const int* __restrict__ lens,
                                             float* __restrict__ part) {
  const int blk = blockIdx.x;
  const int b  = blk >> 5;
  const int et = (blk >> 3) & 3;
  const int tc = blk & 7;
  const int tid = threadIdx.x;
  const int e = et * 256 + tid;
  const int len = lens[b];
  const int tbeg = tc * 256;
  const int tend = min(tbeg + 256, len);
  float a0 = 0.f, a1 = 0.f;
  int t = tbeg;
  for (; t + 2 <= tend; t += 2) {
    a0 = fmaf(wf[b * TT_ALL + t + 0], enc[((size_t)b * TT_ALL + t + 0) * EPROJS + e], a0);
    a1 = fmaf(wf[b * TT_ALL + t + 1], enc[((size_t)b * TT_ALL + t + 1) * EPROJS + e], a1);
  }
  for (; t < tend; ++t)
    a0 = fmaf(wf[b * TT_ALL + t], enc[((size_t)b * TT_ALL + t) * EPROJS + e], a0);
  part[((size_t)b * 8 + tc) * EPROJS + e] = a0 + a1;
}

__global__ __launch_bounds__(256) void k_comb(const float* __restrict__ part,
                                              float* __restrict__ out) {
  const int b = blockIdx.x >> 2, et = blockIdx.x & 3;
  const int e = et * 256 + threadIdx.x;
  float s = 0.f;
#pragma unroll
  for (int tc = 0; tc < 8; ++tc) s += part[((size_t)b * 8 + tc) * EPROJS + e];
  out[OFF_C + b * EPROJS + e] = s;
}

// ---------------------------------------------------------------------------
extern "C" void kernel_launch(void* const* d_in, const int* in_sizes, int n_in,
                              void* d_out, int out_size, void* d_ws, size_t ws_size,
                              hipStream_t stream) {
  const float* enc      = (const float*)d_in[0];
  const int*   lens     = (const int*)d_in[1];
  const float* dec_z    = (const float*)d_in[2];
  const float* att_prev = (const float*)d_in[3];
  const float* att_h    = (const float*)d_in[4];
  const float* att_c    = (const float*)d_in[5];
  const float* W_enc    = (const float*)d_in[6];
  const float* b_enc    = (const float*)d_in[7];
  const float* W_dec    = (const float*)d_in[8];
  const float* W_conv   = (const float*)d_in[9];
  const float* W_ih     = (const float*)d_in[10];
  const float* W_hh     = (const float*)d_in[11];
  const float* W_g      = (const float*)d_in[12];
  const float* b_g      = (const float*)d_in[13];
  (void)b_g;  // cancels inside softmax
  float* out = (float*)d_out;
  float* ws  = (float*)d_ws;

  float* cf   = ws + WS_CF;
  float* v    = ws + WS_V;
  float* ep   = ws + WS_EP;
  float* wf   = ws + WS_WF;
  unsigned short* wtf = (unsigned short*)(ws + WS_WT);
  float* part = ws + WS_PART;
  float* gp   = ws + WS_GP;
  float* dp   = ws + WS_DP;

  k_wprepF    <<<32 * 32, 64, 0, stream>>>(W_enc, wtf);
  k_conv      <<<BB * CH, 256, 0, stream>>>(att_prev, W_conv, cf);
  k_gates     <<<64, 256, 0, stream>>>(att_h, W_hh, gp);
  k_dec       <<<16, 256, 0, stream>>>(dec_z, W_dec, dp);
  k_lstm_v    <<<BB, 256, 0, stream>>>(gp, dp, cf, W_ih, att_c, v, out);
  k_score_mfma<<<BB * 32 * 2, 256, 0, stream>>>(enc, wtf, b_enc, W_g, v, lens, ep);
  k_softmax   <<<BB, 256, 0, stream>>>(ep, lens, wf, out);
  k_ctx       <<<BB * 32, 256, 0, stream>>>(enc, wf, lens, part);
  k_comb      <<<BB * 4, 256, 0, stream>>>(part, out);
}